// Round 6
// baseline (2422.006 us; speedup 1.0000x reference)
//
#include <hip/hip_runtime.h>
#include <hip/hip_bf16.h>
#include <hip/hip_fp16.h>
#include <type_traits>
#include <utility>

// FaceModel: N=500000 nodes, E=3000000 edges, F=128.
// mlp_face(7->128->128,ELU) -> GraphConv1 -> ELU -> 3x(Lin+ELU) ->
// GraphConv2 -> concat(ff,h2) -> Lin(256->128)+ELU -> Lin+ELU -> Lin(128->2).
//
// R6: R5 passed (2419us, absmax 9.8e-4). Profile: 2x atomic scatter = 52% of
// runtime, atomic-throughput-bound (308G atomics/s, WRITE 750MB vs 128MB
// buffer). Replace with CSR built once per call (hist+scan+fill, ~16MB in ws)
// and per-node gather-sum (fp32 accumulate, no atomics, coalesced writes).
// ws_size-adaptive (host branch, constant across calls):
//   >=404MB: 3 act buffers (ff persists; no mlp_face recompute) + CSR
//   >=276MB: 2 act buffers + CSR (mlp_face recomputed for stage2)
//   else   : R5 atomic-scatter fallback.

#define NROWS 500000
#define NEDGE 3000000
#define SCAN_CHUNK 1024
#define NBLK_SCAN ((NROWS + SCAN_CHUNK - 1) / SCAN_CHUNK)   // 489

typedef __hip_bfloat16 bf16;
typedef unsigned short u16;
using short8 = __attribute__((ext_vector_type(8))) short;
using half8  = __attribute__((ext_vector_type(8))) _Float16;
using f32x4  = __attribute__((ext_vector_type(4))) float;

__device__ __forceinline__ float bf2f(u16 s) {
  unsigned u = ((unsigned)s) << 16;
  return __uint_as_float(u);
}
__device__ __forceinline__ u16 f2h_bits(float f) {
  _Float16 h = (_Float16)f;
  return __builtin_bit_cast(u16, h);
}
__device__ __forceinline__ float h2f(u16 b) {
  return (float)__builtin_bit_cast(_Float16, b);
}
__device__ __forceinline__ float eluf(float x) { return x > 0.0f ? x : expm1f(x); }
__device__ __forceinline__ float ldf(const void* p, long i, bool f32) {
  return f32 ? ((const float*)p)[i] : bf2f(((const u16*)p)[i]);
}

// --- f16 packed atomic add with compile-time fallback (atomic path only) ---
template <typename T, typename = void> struct HasUnsafeAdd : std::false_type {};
template <typename T>
struct HasUnsafeAdd<T, std::void_t<decltype(unsafeAtomicAdd(
    std::declval<T*>(), std::declval<T>()))>> : std::true_type {};
template <bool HAS> struct AtomAdd;
template <> struct AtomAdd<true> {
  template <class T> __device__ static void go(T* p, T v) { unsafeAtomicAdd(p, v); }
};
template <> struct AtomAdd<false> {
  template <class T> __device__ static void go(T* p, T v) {
    unsigned* up = reinterpret_cast<unsigned*>(p);
    unsigned old = *up;
    while (true) {
      unsigned assumed = old;
      T cur = __builtin_bit_cast(T, assumed);
      T nw = __hadd2(cur, v);
      old = atomicCAS(up, assumed, __builtin_bit_cast(unsigned, nw));
      if (old == assumed) break;
    }
  }
};
__device__ __forceinline__ void atomAddH2(__half2* p, __half2 v) {
  AtomAdd<HasUnsafeAdd<__half2>::value>::go(p, v);
}

// ---------------------------------------------------------------------------
// Sniff: bf16(0) vs fp32(1) from mf_w0 bit patterns.
// ---------------------------------------------------------------------------
__global__ __launch_bounds__(256) void sniff_kernel(const u16* mf_w0, int* flag) {
  __shared__ int cnt;
  if (threadIdx.x == 0) cnt = 0;
  __syncthreads();
  int local = 0;
  for (int i = threadIdx.x; i < 896; i += 256) {
    int ex = (mf_w0[i] >> 7) & 0xFF;
    if (ex >= 0xC8) local++;
  }
  atomicAdd(&cnt, local);
  __syncthreads();
  if (threadIdx.x == 0) flag[0] = (cnt >= 4) ? 1 : 0;
}

// ---------------------------------------------------------------------------
// Weight transpose into f16 stash: out[slot][n*128+k] = W[k][n].
// ---------------------------------------------------------------------------
__global__ __launch_bounds__(256) void transpose_w(
    const void* p0, const void* p1, const void* p2, const void* p3,
    const void* p4, const void* p5, const void* p6, const void* p7,
    const void* p8, const void* p10, u16* dst, const int* flag)
{
  const void* src = p0; int eoff = 0;
  switch (blockIdx.y) {
    case 1: src = p1; break;  case 2: src = p2; break;
    case 3: src = p3; break;  case 4: src = p4; break;
    case 5: src = p5; break;  case 6: src = p6; break;
    case 7: src = p7; break;  case 8: src = p8; break;
    case 9: src = p8; eoff = 16384; break;
    case 10: src = p10; break;
    default: break;
  }
  const bool f32 = flag[0] != 0;
  u16* out = dst + (size_t)blockIdx.y * 16384;
  for (int i = threadIdx.x + blockIdx.x * 256; i < 16384; i += 2048) {
    int n = i >> 7, k = i & 127;
    long si = eoff + k * 128 + n;
    out[i] = f2h_bits(ldf(src, si, f32));
  }
}

// ---------------------------------------------------------------------------
// Small-tensor prep into fp32 stash (layout as R5).
// ---------------------------------------------------------------------------
__device__ __forceinline__ void cvt_vec(float* dst, const void* src, int n,
                                        bool f32, int tid) {
  for (int i = tid; i < n; i += 256) dst[i] = ldf(src, i, f32);
}
__global__ __launch_bounds__(256) void prep_small(
    const void* w0, const void* b0, const void* b1, const void* g1b,
    const void* g2b, const void* s1b0, const void* s1b1, const void* s1b2,
    const void* s2b0, const void* s2b1, float* fdst, const int* flag)
{
  const bool f32 = flag[0] != 0;
  int tid = threadIdx.x;
  cvt_vec(fdst + 0,    w0,   896, f32, tid);
  cvt_vec(fdst + 896,  b0,   128, f32, tid);
  cvt_vec(fdst + 1024, b1,   128, f32, tid);
  cvt_vec(fdst + 1152, g1b,  128, f32, tid);
  cvt_vec(fdst + 1280, g2b,  128, f32, tid);
  cvt_vec(fdst + 1408, s1b0, 128, f32, tid);
  cvt_vec(fdst + 1536, s1b1, 128, f32, tid);
  cvt_vec(fdst + 1664, s1b2, 128, f32, tid);
  cvt_vec(fdst + 1792, s2b0, 128, f32, tid);
  cvt_vec(fdst + 1920, s2b1, 128, f32, tid);
}

// ---------------------------------------------------------------------------
// CSR build: hist -> scanA/B/C -> fill.  cnt doubles as fill-cursor.
// ---------------------------------------------------------------------------
__global__ __launch_bounds__(256) void hist_kernel(const int* __restrict__ ei,
                                                   int* __restrict__ cnt) {
  int e = blockIdx.x * 256 + threadIdx.x;
  if (e < NEDGE) atomicAdd(&cnt[ei[NEDGE + e]], 1);
}

__global__ __launch_bounds__(256) void scanA(const int* __restrict__ cnt,
                                             int* __restrict__ bsum) {
  __shared__ int sdata[256];
  int b = blockIdx.x, tid = threadIdx.x;
  int base = b * SCAN_CHUNK + tid * 4;
  int s = 0;
#pragma unroll
  for (int t = 0; t < 4; ++t) {
    int i = base + t;
    if (i < NROWS) s += cnt[i];
  }
  sdata[tid] = s;
  __syncthreads();
  for (int off = 128; off > 0; off >>= 1) {
    if (tid < off) sdata[tid] += sdata[tid + off];
    __syncthreads();
  }
  if (tid == 0) bsum[b] = sdata[0];
}

__global__ __launch_bounds__(512) void scanB(int* bsum) {   // in-place -> excl
  __shared__ int sdata[512];
  int tid = threadIdx.x;
  int v = (tid < NBLK_SCAN) ? bsum[tid] : 0;
  sdata[tid] = v;
  __syncthreads();
  for (int off = 1; off < 512; off <<= 1) {
    int val = (tid >= off) ? sdata[tid - off] : 0;
    __syncthreads();
    sdata[tid] += val;
    __syncthreads();
  }
  if (tid < NBLK_SCAN) bsum[tid] = sdata[tid] - v;
}

__global__ __launch_bounds__(256) void scanC(const int* __restrict__ boff,
                                             int* __restrict__ cnt,   // in: counts, out: cursor
                                             int* __restrict__ rowptr) {
  __shared__ int sdata[256];
  int b = blockIdx.x, tid = threadIdx.x;
  int base = b * SCAN_CHUNK + tid * 4;
  int v[4]; int s = 0;
#pragma unroll
  for (int t = 0; t < 4; ++t) {
    int i = base + t;
    v[t] = (i < NROWS) ? cnt[i] : 0;
    s += v[t];
  }
  sdata[tid] = s;
  __syncthreads();
  for (int off = 1; off < 256; off <<= 1) {
    int val = (tid >= off) ? sdata[tid - off] : 0;
    __syncthreads();
    sdata[tid] += val;
    __syncthreads();
  }
  int excl = sdata[tid] - s + boff[b];
#pragma unroll
  for (int t = 0; t < 4; ++t) {
    int i = base + t;
    if (i < NROWS) { rowptr[i] = excl; cnt[i] = excl; }
    excl += v[t];
  }
  if (b == 0 && tid == 0) rowptr[NROWS] = NEDGE;
}

__global__ __launch_bounds__(256) void fill_kernel(const int* __restrict__ ei,
                                                   int* __restrict__ cursor,
                                                   int* __restrict__ adj) {
  int e = blockIdx.x * 256 + threadIdx.x;
  if (e < NEDGE) {
    int d = ei[NEDGE + e];
    int pos = atomicAdd(&cursor[d], 1);
    adj[pos] = ei[e];
  }
}

// ---------------------------------------------------------------------------
// Gather segment-sum: one wave per node; batch 8 neighbor rows so the 8
// random 256B row loads are all in flight before the first accumulate
// (vmcnt pipelining). fp32 accumulate, single coalesced f16 row write.
// ---------------------------------------------------------------------------
__global__ __launch_bounds__(256) void gather_agg(
    const u16* __restrict__ x, const int* __restrict__ rowptr,
    const int* __restrict__ adj, u16* __restrict__ agg)
{
  int wv = threadIdx.x >> 6, lane = threadIdx.x & 63;
  long node = (long)blockIdx.x * 4 + wv;
  if (node >= NROWS) return;
  int beg = rowptr[node], end = rowptr[node + 1];
  float a0 = 0.f, a1 = 0.f;
  for (int j = beg; j < end; j += 8) {
    int take = end - j;
    if (take > 8) take = 8;
    int srcv = (lane < take) ? adj[j + lane] : 0;
    unsigned hb[8];
#pragma unroll
    for (int t = 0; t < 8; ++t) {
      if (t < take) {
        int src = __shfl(srcv, t);
        hb[t] = *reinterpret_cast<const unsigned*>(x + (long)src * 128 + lane * 2);
      }
    }
#pragma unroll
    for (int t = 0; t < 8; ++t) {
      if (t < take) {
        __half2 h = __builtin_bit_cast(__half2, hb[t]);
        a0 += (float)h.x;
        a1 += (float)h.y;
      }
    }
  }
  __half2 r;
  r.x = __float2half(a0);
  r.y = __float2half(a1);
  *reinterpret_cast<__half2*>(agg + node * 128 + lane * 2) = r;
}

// ---------------------------------------------------------------------------
// Atomic scatter (fallback path only).
// ---------------------------------------------------------------------------
__global__ __launch_bounds__(256) void scatter_kernel(
    const u16* __restrict__ x, const int* __restrict__ ei,
    __half2* __restrict__ agg)
{
  int gtid = blockIdx.x * 256 + threadIdx.x;
  int wid = gtid >> 6, lane = gtid & 63;
  int nw = gridDim.x * 4;
  for (int e = wid; e < NEDGE; e += nw) {
    int s = ei[e];
    int d = ei[NEDGE + e];
    __half2 h = *reinterpret_cast<const __half2*>(x + (long)s * 128 + lane * 2);
    atomAddH2(agg + (long)d * 64 + lane, h);
  }
}

// ---------------------------------------------------------------------------
// Swizzled LDS weight staging for MFMA B-fragments (conflict-free b128 reads).
// ---------------------------------------------------------------------------
__device__ __forceinline__ void load_w_swz(const u16* Wt, short* ws, int tid) {
  for (int c = tid; c < 2048; c += 256) {
    int n = c >> 4, kb = c & 15;
    short8 v = *reinterpret_cast<const short8*>(Wt + n * 128 + kb * 8);
    *reinterpret_cast<short8*>(ws + ((n << 4) | (kb ^ (n & 15))) * 8) = v;
  }
}
__device__ __forceinline__ half8 read_b_swz(const short* ws, int col, int kb) {
  short8 v = *reinterpret_cast<const short8*>(ws + ((col << 4) | (kb ^ (col & 15))) * 8);
  return __builtin_bit_cast(half8, v);
}

// ---------------------------------------------------------------------------
// Layer: Y = act( X@W1 + bias [+ X2@W2] ); all f16. In-place safe on X or X2.
// ---------------------------------------------------------------------------
template<bool DUAL, bool ACT>
__global__ __launch_bounds__(256) void layer_kernel(
    const u16* X, const u16* X2,
    const u16* __restrict__ W1t, const u16* __restrict__ W2t,
    const float* __restrict__ bias, u16* Y)
{
  __shared__ __align__(16) short w1s[16384];
  __shared__ __align__(16) short w2s[DUAL ? 16384 : 8];
  int tid = threadIdx.x;
  load_w_swz(W1t, w1s, tid);
  if constexpr (DUAL) load_w_swz(W2t, w2s, tid);
  __syncthreads();

  int wv = tid >> 6, lane = tid & 63;
  int nl = lane & 15, q = lane >> 4;
  long r0 = (long)blockIdx.x * 64 + wv * 16;
  if (r0 >= NROWS) return;
  long arow = r0 + nl;

  f32x4 acc[8];
#pragma unroll
  for (int c = 0; c < 8; ++c) acc[c] = f32x4{0.f, 0.f, 0.f, 0.f};

#pragma unroll
  for (int s = 0; s < 4; ++s) {
    int kofs = s * 32 + q * 8;
    int kb = (s << 2) | q;
    half8 a = __builtin_bit_cast(half8,
        *reinterpret_cast<const short8*>(X + arow * 128 + kofs));
#pragma unroll
    for (int c = 0; c < 8; ++c) {
      half8 b = read_b_swz(w1s, (c << 4) | nl, kb);
      acc[c] = __builtin_amdgcn_mfma_f32_16x16x32_f16(a, b, acc[c], 0, 0, 0);
    }
    if constexpr (DUAL) {
      half8 a2 = __builtin_bit_cast(half8,
          *reinterpret_cast<const short8*>(X2 + arow * 128 + kofs));
#pragma unroll
      for (int c = 0; c < 8; ++c) {
        half8 b2 = read_b_swz(w2s, (c << 4) | nl, kb);
        acc[c] = __builtin_amdgcn_mfma_f32_16x16x32_f16(a2, b2, acc[c], 0, 0, 0);
      }
    }
  }

#pragma unroll
  for (int c = 0; c < 8; ++c) {
    float bv = bias[(c << 4) | nl];
#pragma unroll
    for (int r = 0; r < 4; ++r) {
      float o = acc[c][r] + bv;
      if constexpr (ACT) o = eluf(o);
      Y[(r0 + q * 4 + r) * 128 + (c << 4) + nl] = f2h_bits(o);
    }
  }
}

// ---------------------------------------------------------------------------
// mlp_face: layer0 (7->128 VALU + ELU in LDS), layer1 (128->128 MFMA + ELU).
// ---------------------------------------------------------------------------
__global__ __launch_bounds__(256) void mlp_face_kernel(
    const void* hv, const float* __restrict__ fsm,
    const u16* __restrict__ w1t, u16* ff, const int* flag)
{
  __shared__ __align__(16) short w1s[16384];
  __shared__ __align__(16) short act0[64 * 136];
  __shared__ float hvs[448];
  __shared__ float w0s[7 * 128];
  __shared__ float b0s[128];

  const bool f32 = flag[0] != 0;
  int tid = threadIdx.x;
  load_w_swz(w1t, w1s, tid);
  long base = (long)blockIdx.x * 64;
  for (int i = tid; i < 448; i += 256) {
    long g = base * 7 + i;
    hvs[i] = (g < (long)NROWS * 7) ? ldf(hv, g, f32) : 0.0f;
  }
  for (int i = tid; i < 896; i += 256) w0s[i] = fsm[i];
  if (tid < 128) b0s[tid] = fsm[896 + tid];
  __syncthreads();

  for (int idx = tid; idx < 8192; idx += 256) {
    int n = idx >> 7, c = idx & 127;
    float s = b0s[c];
#pragma unroll
    for (int k = 0; k < 7; ++k) s += hvs[n * 7 + k] * w0s[k * 128 + c];
    act0[n * 136 + c] = (short)f2h_bits(eluf(s));
  }
  __syncthreads();

  int wv = tid >> 6, lane = tid & 63;
  int nl = lane & 15, q = lane >> 4;
  long r0 = base + wv * 16;
  if (r0 >= NROWS) return;

  f32x4 acc[8];
#pragma unroll
  for (int c = 0; c < 8; ++c) acc[c] = f32x4{0.f, 0.f, 0.f, 0.f};

#pragma unroll
  for (int s = 0; s < 4; ++s) {
    int kofs = s * 32 + q * 8;
    int kb = (s << 2) | q;
    half8 a = __builtin_bit_cast(half8,
        *reinterpret_cast<const short8*>(&act0[(wv * 16 + nl) * 136 + kofs]));
#pragma unroll
    for (int c = 0; c < 8; ++c) {
      half8 b = read_b_swz(w1s, (c << 4) | nl, kb);
      acc[c] = __builtin_amdgcn_mfma_f32_16x16x32_f16(a, b, acc[c], 0, 0, 0);
    }
  }
#pragma unroll
  for (int c = 0; c < 8; ++c) {
    float bv = fsm[1024 + ((c << 4) | nl)];
#pragma unroll
    for (int r = 0; r < 4; ++r) {
      float o = eluf(acc[c][r] + bv);
      ff[(r0 + q * 4 + r) * 128 + (c << 4) + nl] = f2h_bits(o);
    }
  }
}

// ---------------------------------------------------------------------------
// Final: out[n][j] = sum_c x[n][c]*W[c][j] + b[j], j<2. fp32/bf16 per flag.
// ---------------------------------------------------------------------------
__global__ __launch_bounds__(256) void final_kernel(
    const u16* __restrict__ x, const void* w2, const void* b2,
    void* out, const int* flag)
{
  __shared__ float w2s[256];
  __shared__ float b2s[2];
  const bool f32 = flag[0] != 0;
  int tid = threadIdx.x;
  w2s[tid] = ldf(w2, tid, f32);
  if (tid < 2) b2s[tid] = ldf(b2, tid, f32);
  __syncthreads();
  long node = (long)blockIdx.x * 64 + (tid >> 2);
  int q = tid & 3;
  if (node >= NROWS) return;
  const u16* xr = x + node * 128 + q * 32;
  float p0 = 0.f, p1 = 0.f;
#pragma unroll
  for (int i = 0; i < 4; ++i) {
    short8 v = *reinterpret_cast<const short8*>(xr + i * 8);
#pragma unroll
    for (int j = 0; j < 8; ++j) {
      float f = h2f((u16)v[j]);
      int cidx = q * 32 + i * 8 + j;
      p0 += f * w2s[cidx * 2];
      p1 += f * w2s[cidx * 2 + 1];
    }
  }
  p0 += __shfl_xor(p0, 1); p0 += __shfl_xor(p0, 2);
  p1 += __shfl_xor(p1, 1); p1 += __shfl_xor(p1, 2);
  if (q == 0) {
    float o0 = p0 + b2s[0], o1 = p1 + b2s[1];
    if (f32) {
      ((float*)out)[node * 2]     = o0;
      ((float*)out)[node * 2 + 1] = o1;
    } else {
      ((bf16*)out)[node * 2]     = __float2bfloat16(o0);
      ((bf16*)out)[node * 2 + 1] = __float2bfloat16(o1);
    }
  }
}

// ---------------------------------------------------------------------------
extern "C" void kernel_launch(void* const* d_in, const int* in_sizes, int n_in,
                              void* d_out, int out_size, void* d_ws, size_t ws_size,
                              hipStream_t stream) {
  const void* hv        = d_in[0];
  const int*  ei        = (const int*)d_in[1];
  const void* mf_w0     = d_in[2];
  const void* mf_b0     = d_in[3];
  const void* mf_w1     = d_in[4];
  const void* mf_b1     = d_in[5];
  const void* g1_rel_w  = d_in[6];
  const void* g1_rel_b  = d_in[7];
  const void* g1_root_w = d_in[8];
  const void* g2_rel_w  = d_in[9];
  const void* g2_rel_b  = d_in[10];
  const void* g2_root_w = d_in[11];
  const void* s1_w0     = d_in[12];
  const void* s1_b0     = d_in[13];
  const void* s1_w1     = d_in[14];
  const void* s1_b1     = d_in[15];
  const void* s1_w2     = d_in[16];
  const void* s1_b2     = d_in[17];
  const void* s2_w0     = d_in[18];
  const void* s2_b0     = d_in[19];
  const void* s2_w1     = d_in[20];
  const void* s2_b1     = d_in[21];
  const void* s2_w2     = d_in[22];
  const void* s2_b2     = d_in[23];

  constexpr size_t ACT_BYTES  = (size_t)NROWS * 128 * 2;       // 128e6 B
  constexpr size_t CUR_BYTES  = ((size_t)NROWS * 4 + 255) & ~255ull;
  constexpr size_t ROW_BYTES  = ((size_t)(NROWS + 1) * 4 + 255) & ~255ull;
  constexpr size_t ADJ_BYTES  = (size_t)NEDGE * 4;
  constexpr size_t CSR_BYTES  = CUR_BYTES + ROW_BYTES + ADJ_BYTES;  // ~16e6 B

  char* ws = (char*)d_ws;
  u16* A = (u16*)ws;                        // chain buffer
  u16* G = (u16*)(ws + ACT_BYTES);          // agg / second buffer

  const bool BIG = ws_size >= 3 * ACT_BYTES + CSR_BYTES + (16u << 20);
  const bool CSR = BIG || ws_size >= 2 * ACT_BYTES + CSR_BYTES + (4u << 20);
  u16* C = BIG ? (u16*)(ws + 2 * ACT_BYTES) : nullptr;         // persistent ff
  char* csr = ws + (BIG ? 3 : 2) * ACT_BYTES;
  int* cursor = (int*)csr;                       // counts -> fill cursor
  int* rowptr = (int*)(csr + CUR_BYTES);
  int* adj    = (int*)(csr + CUR_BYTES + ROW_BYTES);

  // Stash in d_out (>=2MB either dtype world): f16 weightsT + fp32 smalls +
  // flag + scan block-sums. Fully consumed before final_kernel overwrites.
  char*  stash = (char*)d_out;
  u16*   wT    = (u16*)stash;                       // 360448 B
  float* fsm   = (float*)(stash + 360448);          // 8192 B
  int*   flag  = (int*)(stash + 376832);
  int*   bsum  = (int*)(stash + 380928);            // NBLK_SCAN ints

  u16* mf_w1T   = wT + 0 * 16384;
  u16* g1_relT  = wT + 1 * 16384;
  u16* g1_rootT = wT + 2 * 16384;
  u16* s1_w0T   = wT + 3 * 16384;
  u16* s1_w1T   = wT + 4 * 16384;
  u16* s1_w2T   = wT + 5 * 16384;
  u16* g2_relT  = wT + 6 * 16384;
  u16* g2_rootT = wT + 7 * 16384;
  u16* s2w0loT  = wT + 8 * 16384;
  u16* s2w0hiT  = wT + 9 * 16384;
  u16* s2_w1T   = wT + 10 * 16384;

  sniff_kernel<<<1, 256, 0, stream>>>((const u16*)mf_w0, flag);
  transpose_w<<<dim3(8, 11), 256, 0, stream>>>(
      mf_w1, g1_rel_w, g1_root_w, s1_w0, s1_w1, s1_w2,
      g2_rel_w, g2_root_w, s2_w0, s2_w1, wT, flag);
  prep_small<<<1, 256, 0, stream>>>(
      mf_w0, mf_b0, mf_b1, g1_rel_b, g2_rel_b,
      s1_b0, s1_b1, s1_b2, s2_b0, s2_b1, fsm, flag);

  const int gb  = (NROWS + 63) / 64;        // 7813 (64 rows/block)
  const int ge  = (NEDGE + 255) / 256;      // 11719 (edge kernels)
  const int gn  = (NROWS + 3) / 4;          // 125000 (gather, 4 waves/block)

  if (CSR) {
    // ---- build CSR once (reused by both GraphConvs) ----
    (void)hipMemsetAsync(cursor, 0, (size_t)NROWS * 4, stream);
    hist_kernel<<<ge, 256, 0, stream>>>(ei, cursor);
    scanA<<<NBLK_SCAN, 256, 0, stream>>>(cursor, bsum);
    scanB<<<1, 512, 0, stream>>>(bsum);
    scanC<<<NBLK_SCAN, 256, 0, stream>>>(bsum, cursor, rowptr);
    fill_kernel<<<ge, 256, 0, stream>>>(ei, cursor, adj);

    u16* ff = BIG ? C : A;
    mlp_face_kernel<<<gb, 256, 0, stream>>>(hv, fsm, mf_w1T, ff, flag);
    gather_agg<<<gn, 256, 0, stream>>>(ff, rowptr, adj, G);
    layer_kernel<true,  true ><<<gb, 256, 0, stream>>>(G, ff, g1_relT, g1_rootT, fsm + 1152, A);
    layer_kernel<false, true ><<<gb, 256, 0, stream>>>(A, nullptr, s1_w0T, nullptr, fsm + 1408, A);
    layer_kernel<false, true ><<<gb, 256, 0, stream>>>(A, nullptr, s1_w1T, nullptr, fsm + 1536, A);
    layer_kernel<false, true ><<<gb, 256, 0, stream>>>(A, nullptr, s1_w2T, nullptr, fsm + 1664, A);
    gather_agg<<<gn, 256, 0, stream>>>(A, rowptr, adj, G);
    layer_kernel<true,  false><<<gb, 256, 0, stream>>>(G, A, g2_relT, g2_rootT, fsm + 1280, A);
    u16* fb;
    if (BIG) {
      fb = C;                                   // ff persisted
    } else {
      mlp_face_kernel<<<gb, 256, 0, stream>>>(hv, fsm, mf_w1T, G, flag);
      fb = G;                                   // recomputed
    }
    layer_kernel<true,  true ><<<gb, 256, 0, stream>>>(fb, A, s2w0loT, s2w0hiT, fsm + 1792, fb);
    layer_kernel<false, true ><<<gb, 256, 0, stream>>>(fb, nullptr, s2_w1T, nullptr, fsm + 1920, fb);
    final_kernel<<<gb, 256, 0, stream>>>(fb, s2_w2, s2_b2, d_out, flag);
  } else {
    // ---- R5 fallback: atomic scatter, 256MB ws ----
    mlp_face_kernel<<<gb, 256, 0, stream>>>(hv, fsm, mf_w1T, A, flag);
    (void)hipMemsetAsync(G, 0, ACT_BYTES, stream);
    scatter_kernel<<<4096, 256, 0, stream>>>(A, ei, (__half2*)G);
    layer_kernel<true,  true ><<<gb, 256, 0, stream>>>(G, A, g1_relT, g1_rootT, fsm + 1152, A);
    layer_kernel<false, true ><<<gb, 256, 0, stream>>>(A, nullptr, s1_w0T, nullptr, fsm + 1408, A);
    layer_kernel<false, true ><<<gb, 256, 0, stream>>>(A, nullptr, s1_w1T, nullptr, fsm + 1536, A);
    layer_kernel<false, true ><<<gb, 256, 0, stream>>>(A, nullptr, s1_w2T, nullptr, fsm + 1664, A);
    (void)hipMemsetAsync(G, 0, ACT_BYTES, stream);
    scatter_kernel<<<4096, 256, 0, stream>>>(A, ei, (__half2*)G);
    layer_kernel<true,  false><<<gb, 256, 0, stream>>>(G, A, g2_relT, g2_rootT, fsm + 1280, A);
    mlp_face_kernel<<<gb, 256, 0, stream>>>(hv, fsm, mf_w1T, G, flag);
    layer_kernel<true,  true ><<<gb, 256, 0, stream>>>(G, A, s2w0loT, s2w0hiT, fsm + 1792, G);
    layer_kernel<false, true ><<<gb, 256, 0, stream>>>(G, nullptr, s2_w1T, nullptr, fsm + 1920, G);
    final_kernel<<<gb, 256, 0, stream>>>(G, s2_w2, s2_b2, d_out, flag);
  }
}

// Round 7
// 1950.869 us; speedup vs baseline: 1.2415x; 1.2415x over previous
//
#include <hip/hip_runtime.h>
#include <hip/hip_bf16.h>
#include <hip/hip_fp16.h>
#include <type_traits>
#include <utility>

// FaceModel: N=500000 nodes, E=3000000 edges, F=128.
// mlp_face(7->128->128,ELU) -> GraphConv1 -> ELU -> 3x(Lin+ELU) ->
// GraphConv2 -> concat(ff,h2) -> Lin(256->128)+ELU -> Lin+ELU -> Lin(128->2).
// Inputs/outputs fp32 (established R4->R6); internals f16, fp32 accumulate.
//
// R7: R6's CSR tier never ran (ws < 276e6; known ws in [256e6, 276.2e6)).
// Slim CSR to fit 256MiB: rowptr eliminated (cursor-as-end-offsets trick),
// cursor lives in the d_out stash (fp32 world confirmed -> d_out = 4e6 B).
// ws = A(128e6) + G(128e6) + adj(12e6) = 268.0e6. Atomic-scatter fallback
// kept for ws < 268e6.

#define NROWS 500000
#define NEDGE 3000000
#define SCAN_CHUNK 1024
#define NBLK_SCAN ((NROWS + SCAN_CHUNK - 1) / SCAN_CHUNK)   // 489

typedef unsigned short u16;
using short8 = __attribute__((ext_vector_type(8))) short;
using half8  = __attribute__((ext_vector_type(8))) _Float16;
using f32x4  = __attribute__((ext_vector_type(4))) float;

__device__ __forceinline__ u16 f2h_bits(float f) {
  _Float16 h = (_Float16)f;
  return __builtin_bit_cast(u16, h);
}
__device__ __forceinline__ float h2f(u16 b) {
  return (float)__builtin_bit_cast(_Float16, b);
}
__device__ __forceinline__ float eluf(float x) { return x > 0.0f ? x : expm1f(x); }

// --- f16 packed atomic add with compile-time fallback (scatter path only) --
template <typename T, typename = void> struct HasUnsafeAdd : std::false_type {};
template <typename T>
struct HasUnsafeAdd<T, std::void_t<decltype(unsafeAtomicAdd(
    std::declval<T*>(), std::declval<T>()))>> : std::true_type {};
template <bool HAS> struct AtomAdd;
template <> struct AtomAdd<true> {
  template <class T> __device__ static void go(T* p, T v) { unsafeAtomicAdd(p, v); }
};
template <> struct AtomAdd<false> {
  template <class T> __device__ static void go(T* p, T v) {
    unsigned* up = reinterpret_cast<unsigned*>(p);
    unsigned old = *up;
    while (true) {
      unsigned assumed = old;
      T cur = __builtin_bit_cast(T, assumed);
      T nw = __hadd2(cur, v);
      old = atomicCAS(up, assumed, __builtin_bit_cast(unsigned, nw));
      if (old == assumed) break;
    }
  }
};
__device__ __forceinline__ void atomAddH2(__half2* p, __half2 v) {
  AtomAdd<HasUnsafeAdd<__half2>::value>::go(p, v);
}

// ---------------------------------------------------------------------------
// Weight transpose fp32 -> f16 stash: out[slot][n*128+k] = W[k][n].
// Slots: 0 mf_w1, 1 g1_rel, 2 g1_root, 3 s1_w0, 4 s1_w1, 5 s1_w2,
//        6 g2_rel, 7 g2_root, 8 s2_w0[0:128], 9 s2_w0[128:256], 10 s2_w1
// ---------------------------------------------------------------------------
__global__ __launch_bounds__(256) void transpose_w(
    const float* p0, const float* p1, const float* p2, const float* p3,
    const float* p4, const float* p5, const float* p6, const float* p7,
    const float* p8, const float* p10, u16* dst)
{
  const float* src = p0; int eoff = 0;
  switch (blockIdx.y) {
    case 1: src = p1; break;  case 2: src = p2; break;
    case 3: src = p3; break;  case 4: src = p4; break;
    case 5: src = p5; break;  case 6: src = p6; break;
    case 7: src = p7; break;  case 8: src = p8; break;
    case 9: src = p8; eoff = 16384; break;
    case 10: src = p10; break;
    default: break;
  }
  u16* out = dst + (size_t)blockIdx.y * 16384;
  for (int i = threadIdx.x + blockIdx.x * 256; i < 16384; i += 2048) {
    int n = i >> 7, k = i & 127;
    out[i] = f2h_bits(src[eoff + k * 128 + n]);
  }
}

// ---------------------------------------------------------------------------
// CSR build: hist -> scanA/B/C -> fill.  Single array `cur`:
//   after scanC: cur[i] = start offset of node i
//   after fill : cur[i] = end offset of node i  (= start of i+1)
// ---------------------------------------------------------------------------
__global__ __launch_bounds__(256) void hist_kernel(const int* __restrict__ ei,
                                                   int* __restrict__ cur) {
  int e = blockIdx.x * 256 + threadIdx.x;
  if (e < NEDGE) atomicAdd(&cur[ei[NEDGE + e]], 1);
}

__global__ __launch_bounds__(256) void scanA(const int* __restrict__ cur,
                                             int* __restrict__ bsum) {
  __shared__ int sdata[256];
  int b = blockIdx.x, tid = threadIdx.x;
  int base = b * SCAN_CHUNK + tid * 4;
  int s = 0;
#pragma unroll
  for (int t = 0; t < 4; ++t) {
    int i = base + t;
    if (i < NROWS) s += cur[i];
  }
  sdata[tid] = s;
  __syncthreads();
  for (int off = 128; off > 0; off >>= 1) {
    if (tid < off) sdata[tid] += sdata[tid + off];
    __syncthreads();
  }
  if (tid == 0) bsum[b] = sdata[0];
}

__global__ __launch_bounds__(512) void scanB(int* bsum) {   // in-place -> excl
  __shared__ int sdata[512];
  int tid = threadIdx.x;
  int v = (tid < NBLK_SCAN) ? bsum[tid] : 0;
  sdata[tid] = v;
  __syncthreads();
  for (int off = 1; off < 512; off <<= 1) {
    int val = (tid >= off) ? sdata[tid - off] : 0;
    __syncthreads();
    sdata[tid] += val;
    __syncthreads();
  }
  if (tid < NBLK_SCAN) bsum[tid] = sdata[tid] - v;
}

__global__ __launch_bounds__(256) void scanC(const int* __restrict__ boff,
                                             int* __restrict__ cur) {
  __shared__ int sdata[256];
  int b = blockIdx.x, tid = threadIdx.x;
  int base = b * SCAN_CHUNK + tid * 4;
  int v[4]; int s = 0;
#pragma unroll
  for (int t = 0; t < 4; ++t) {
    int i = base + t;
    v[t] = (i < NROWS) ? cur[i] : 0;
    s += v[t];
  }
  sdata[tid] = s;
  __syncthreads();
  for (int off = 1; off < 256; off <<= 1) {
    int val = (tid >= off) ? sdata[tid - off] : 0;
    __syncthreads();
    sdata[tid] += val;
    __syncthreads();
  }
  int excl = sdata[tid] - s + boff[b];
#pragma unroll
  for (int t = 0; t < 4; ++t) {
    int i = base + t;
    if (i < NROWS) cur[i] = excl;
    excl += v[t];
  }
}

__global__ __launch_bounds__(256) void fill_kernel(const int* __restrict__ ei,
                                                   int* __restrict__ cur,
                                                   int* __restrict__ adj) {
  int e = blockIdx.x * 256 + threadIdx.x;
  if (e < NEDGE) {
    int d = ei[NEDGE + e];
    int pos = atomicAdd(&cur[d], 1);
    adj[pos] = ei[e];
  }
}

// ---------------------------------------------------------------------------
// Gather segment-sum: one wave per node; batch 8 neighbor rows so all 8
// random 256B row loads are in flight before accumulation (vmcnt pipelining).
// fp32 accumulate, single coalesced f16 row write. cend = end offsets.
// ---------------------------------------------------------------------------
__global__ __launch_bounds__(256) void gather_agg(
    const u16* __restrict__ x, const int* __restrict__ cend,
    const int* __restrict__ adj, u16* __restrict__ agg)
{
  int wv = threadIdx.x >> 6, lane = threadIdx.x & 63;
  long node = (long)blockIdx.x * 4 + wv;
  if (node >= NROWS) return;
  int beg = (node == 0) ? 0 : cend[node - 1];
  int end = cend[node];
  float a0 = 0.f, a1 = 0.f;
  for (int j = beg; j < end; j += 8) {
    int take = end - j;
    if (take > 8) take = 8;
    int srcv = (lane < take) ? adj[j + lane] : 0;
    unsigned hb[8];
#pragma unroll
    for (int t = 0; t < 8; ++t) {
      if (t < take) {
        int src = __shfl(srcv, t);
        hb[t] = *reinterpret_cast<const unsigned*>(x + (long)src * 128 + lane * 2);
      }
    }
#pragma unroll
    for (int t = 0; t < 8; ++t) {
      if (t < take) {
        __half2 h = __builtin_bit_cast(__half2, hb[t]);
        a0 += (float)h.x;
        a1 += (float)h.y;
      }
    }
  }
  __half2 r;
  r.x = __float2half(a0);
  r.y = __float2half(a1);
  *reinterpret_cast<__half2*>(agg + node * 128 + lane * 2) = r;
}

// ---------------------------------------------------------------------------
// Atomic scatter (fallback path only).
// ---------------------------------------------------------------------------
__global__ __launch_bounds__(256) void scatter_kernel(
    const u16* __restrict__ x, const int* __restrict__ ei,
    __half2* __restrict__ agg)
{
  int gtid = blockIdx.x * 256 + threadIdx.x;
  int wid = gtid >> 6, lane = gtid & 63;
  int nw = gridDim.x * 4;
  for (int e = wid; e < NEDGE; e += nw) {
    int s = ei[e];
    int d = ei[NEDGE + e];
    __half2 h = *reinterpret_cast<const __half2*>(x + (long)s * 128 + lane * 2);
    atomAddH2(agg + (long)d * 64 + lane, h);
  }
}

// ---------------------------------------------------------------------------
// Swizzled LDS weight staging for MFMA B-fragments (conflict-free b128 reads).
// ---------------------------------------------------------------------------
__device__ __forceinline__ void load_w_swz(const u16* Wt, short* ws, int tid) {
  for (int c = tid; c < 2048; c += 256) {
    int n = c >> 4, kb = c & 15;
    short8 v = *reinterpret_cast<const short8*>(Wt + n * 128 + kb * 8);
    *reinterpret_cast<short8*>(ws + ((n << 4) | (kb ^ (n & 15))) * 8) = v;
  }
}
__device__ __forceinline__ half8 read_b_swz(const short* ws, int col, int kb) {
  short8 v = *reinterpret_cast<const short8*>(ws + ((col << 4) | (kb ^ (col & 15))) * 8);
  return __builtin_bit_cast(half8, v);
}

// ---------------------------------------------------------------------------
// Layer: Y = act( X@W1 + bias [+ X2@W2] ); all f16, fp32 bias from d_in.
// 256 thr = 4 waves, 64 rows/block, 16 rows/wave. In-place safe on X or X2.
// ---------------------------------------------------------------------------
template<bool DUAL, bool ACT>
__global__ __launch_bounds__(256) void layer_kernel(
    const u16* X, const u16* X2,
    const u16* __restrict__ W1t, const u16* __restrict__ W2t,
    const float* __restrict__ bias, u16* Y)
{
  __shared__ __align__(16) short w1s[16384];
  __shared__ __align__(16) short w2s[DUAL ? 16384 : 8];
  int tid = threadIdx.x;
  load_w_swz(W1t, w1s, tid);
  if constexpr (DUAL) load_w_swz(W2t, w2s, tid);
  __syncthreads();

  int wv = tid >> 6, lane = tid & 63;
  int nl = lane & 15, q = lane >> 4;
  long r0 = (long)blockIdx.x * 64 + wv * 16;
  if (r0 >= NROWS) return;
  long arow = r0 + nl;

  f32x4 acc[8];
#pragma unroll
  for (int c = 0; c < 8; ++c) acc[c] = f32x4{0.f, 0.f, 0.f, 0.f};

#pragma unroll
  for (int s = 0; s < 4; ++s) {
    int kofs = s * 32 + q * 8;
    int kb = (s << 2) | q;
    half8 a = __builtin_bit_cast(half8,
        *reinterpret_cast<const short8*>(X + arow * 128 + kofs));
#pragma unroll
    for (int c = 0; c < 8; ++c) {
      half8 b = read_b_swz(w1s, (c << 4) | nl, kb);
      acc[c] = __builtin_amdgcn_mfma_f32_16x16x32_f16(a, b, acc[c], 0, 0, 0);
    }
    if constexpr (DUAL) {
      half8 a2 = __builtin_bit_cast(half8,
          *reinterpret_cast<const short8*>(X2 + arow * 128 + kofs));
#pragma unroll
      for (int c = 0; c < 8; ++c) {
        half8 b2 = read_b_swz(w2s, (c << 4) | nl, kb);
        acc[c] = __builtin_amdgcn_mfma_f32_16x16x32_f16(a2, b2, acc[c], 0, 0, 0);
      }
    }
  }

#pragma unroll
  for (int c = 0; c < 8; ++c) {
    float bv = bias[(c << 4) | nl];
#pragma unroll
    for (int r = 0; r < 4; ++r) {
      float o = acc[c][r] + bv;
      if constexpr (ACT) o = eluf(o);
      Y[(r0 + q * 4 + r) * 128 + (c << 4) + nl] = f2h_bits(o);
    }
  }
}

// ---------------------------------------------------------------------------
// mlp_face: layer0 (7->128 VALU + ELU in LDS), layer1 (128->128 MFMA + ELU).
// hv/w0/b0/b1 read fp32 directly from d_in.
// ---------------------------------------------------------------------------
__global__ __launch_bounds__(256) void mlp_face_kernel(
    const float* __restrict__ hv, const float* __restrict__ w0,
    const float* __restrict__ b0, const u16* __restrict__ w1t,
    const float* __restrict__ b1, u16* ff)
{
  __shared__ __align__(16) short w1s[16384];
  __shared__ __align__(16) short act0[64 * 136];
  __shared__ float hvs[448];
  __shared__ float w0s[7 * 128];
  __shared__ float b0s[128];

  int tid = threadIdx.x;
  load_w_swz(w1t, w1s, tid);
  long base = (long)blockIdx.x * 64;
  for (int i = tid; i < 448; i += 256) {
    long g = base * 7 + i;
    hvs[i] = (g < (long)NROWS * 7) ? hv[g] : 0.0f;
  }
  for (int i = tid; i < 896; i += 256) w0s[i] = w0[i];
  if (tid < 128) b0s[tid] = b0[tid];
  __syncthreads();

  for (int idx = tid; idx < 8192; idx += 256) {
    int n = idx >> 7, c = idx & 127;
    float s = b0s[c];
#pragma unroll
    for (int k = 0; k < 7; ++k) s += hvs[n * 7 + k] * w0s[k * 128 + c];
    act0[n * 136 + c] = (short)f2h_bits(eluf(s));
  }
  __syncthreads();

  int wv = tid >> 6, lane = tid & 63;
  int nl = lane & 15, q = lane >> 4;
  long r0 = base + wv * 16;
  if (r0 >= NROWS) return;

  f32x4 acc[8];
#pragma unroll
  for (int c = 0; c < 8; ++c) acc[c] = f32x4{0.f, 0.f, 0.f, 0.f};

#pragma unroll
  for (int s = 0; s < 4; ++s) {
    int kofs = s * 32 + q * 8;
    int kb = (s << 2) | q;
    half8 a = __builtin_bit_cast(half8,
        *reinterpret_cast<const short8*>(&act0[(wv * 16 + nl) * 136 + kofs]));
#pragma unroll
    for (int c = 0; c < 8; ++c) {
      half8 b = read_b_swz(w1s, (c << 4) | nl, kb);
      acc[c] = __builtin_amdgcn_mfma_f32_16x16x32_f16(a, b, acc[c], 0, 0, 0);
    }
  }
#pragma unroll
  for (int c = 0; c < 8; ++c) {
    float bv = b1[(c << 4) | nl];
#pragma unroll
    for (int r = 0; r < 4; ++r) {
      float o = eluf(acc[c][r] + bv);
      ff[(r0 + q * 4 + r) * 128 + (c << 4) + nl] = f2h_bits(o);
    }
  }
}

// ---------------------------------------------------------------------------
// Final: out[n][j] = sum_c x[n][c]*W[c][j] + b[j], j<2. fp32 out.
// ---------------------------------------------------------------------------
__global__ __launch_bounds__(256) void final_kernel(
    const u16* __restrict__ x, const float* __restrict__ w2,
    const float* __restrict__ b2, float* __restrict__ out)
{
  __shared__ float w2s[256];
  __shared__ float b2s[2];
  int tid = threadIdx.x;
  w2s[tid] = w2[tid];
  if (tid < 2) b2s[tid] = b2[tid];
  __syncthreads();
  long node = (long)blockIdx.x * 64 + (tid >> 2);
  int q = tid & 3;
  if (node >= NROWS) return;
  const u16* xr = x + node * 128 + q * 32;
  float p0 = 0.f, p1 = 0.f;
#pragma unroll
  for (int i = 0; i < 4; ++i) {
    short8 v = *reinterpret_cast<const short8*>(xr + i * 8);
#pragma unroll
    for (int j = 0; j < 8; ++j) {
      float f = h2f((u16)v[j]);
      int cidx = q * 32 + i * 8 + j;
      p0 += f * w2s[cidx * 2];
      p1 += f * w2s[cidx * 2 + 1];
    }
  }
  p0 += __shfl_xor(p0, 1); p0 += __shfl_xor(p0, 2);
  p1 += __shfl_xor(p1, 1); p1 += __shfl_xor(p1, 2);
  if (q == 0) {
    out[node * 2]     = p0 + b2s[0];
    out[node * 2 + 1] = p1 + b2s[1];
  }
}

// ---------------------------------------------------------------------------
extern "C" void kernel_launch(void* const* d_in, const int* in_sizes, int n_in,
                              void* d_out, int out_size, void* d_ws, size_t ws_size,
                              hipStream_t stream) {
  const float* hv        = (const float*)d_in[0];
  const int*   ei        = (const int*)d_in[1];
  const float* mf_w0     = (const float*)d_in[2];
  const float* mf_b0     = (const float*)d_in[3];
  const float* mf_w1     = (const float*)d_in[4];
  const float* mf_b1     = (const float*)d_in[5];
  const float* g1_rel_w  = (const float*)d_in[6];
  const float* g1_rel_b  = (const float*)d_in[7];
  const float* g1_root_w = (const float*)d_in[8];
  const float* g2_rel_w  = (const float*)d_in[9];
  const float* g2_rel_b  = (const float*)d_in[10];
  const float* g2_root_w = (const float*)d_in[11];
  const float* s1_w0     = (const float*)d_in[12];
  const float* s1_b0     = (const float*)d_in[13];
  const float* s1_w1     = (const float*)d_in[14];
  const float* s1_b1     = (const float*)d_in[15];
  const float* s1_w2     = (const float*)d_in[16];
  const float* s1_b2     = (const float*)d_in[17];
  const float* s2_w0     = (const float*)d_in[18];
  const float* s2_b0     = (const float*)d_in[19];
  const float* s2_w1     = (const float*)d_in[20];
  const float* s2_b1     = (const float*)d_in[21];
  const float* s2_w2     = (const float*)d_in[22];
  const float* s2_b2     = (const float*)d_in[23];

  constexpr size_t ACT_BYTES = (size_t)NROWS * 128 * 2;     // 128e6 B
  constexpr size_t ADJ_BYTES = (size_t)NEDGE * 4;           // 12e6 B

  char* ws = (char*)d_ws;
  u16* A   = (u16*)ws;                        // chain buffer
  u16* G   = (u16*)(ws + ACT_BYTES);          // agg / second buffer
  int* adj = (int*)(ws + 2 * ACT_BYTES);      // CSR adjacency (12e6)
  const bool CSR = ws_size >= 2 * ACT_BYTES + ADJ_BYTES;    // 268e6

  // Stash in d_out (fp32 world: 4e6 B): f16 weightsT + scan bsum + cursor.
  // Fully consumed before final_kernel overwrites d_out (same stream).
  char* stash = (char*)d_out;
  u16*  wT    = (u16*)stash;                      // 360,448 B
  int*  bsum  = (int*)(stash + 360448);           // 489*4 = 1,956 B
  int*  cur   = (int*)(stash + 362496);           // 2,000,000 B -> ends 2,362,496

  u16* mf_w1T   = wT + 0 * 16384;
  u16* g1_relT  = wT + 1 * 16384;
  u16* g1_rootT = wT + 2 * 16384;
  u16* s1_w0T   = wT + 3 * 16384;
  u16* s1_w1T   = wT + 4 * 16384;
  u16* s1_w2T   = wT + 5 * 16384;
  u16* g2_relT  = wT + 6 * 16384;
  u16* g2_rootT = wT + 7 * 16384;
  u16* s2w0loT  = wT + 8 * 16384;
  u16* s2w0hiT  = wT + 9 * 16384;
  u16* s2_w1T   = wT + 10 * 16384;

  transpose_w<<<dim3(8, 11), 256, 0, stream>>>(
      mf_w1, g1_rel_w, g1_root_w, s1_w0, s1_w1, s1_w2,
      g2_rel_w, g2_root_w, s2_w0, s2_w1, wT);

  const int gb = (NROWS + 63) / 64;        // 7813
  const int ge = (NEDGE + 255) / 256;      // 11719
  const int gn = (NROWS + 3) / 4;          // 125000

  if (CSR) {
    // ---- build CSR once (reused by both GraphConvs) ----
    (void)hipMemsetAsync(cur, 0, (size_t)NROWS * 4, stream);
    hist_kernel<<<ge, 256, 0, stream>>>(ei, cur);
    scanA<<<NBLK_SCAN, 256, 0, stream>>>(cur, bsum);
    scanB<<<1, 512, 0, stream>>>(bsum);
    scanC<<<NBLK_SCAN, 256, 0, stream>>>(bsum, cur);
    fill_kernel<<<ge, 256, 0, stream>>>(ei, cur, adj);   // cur -> end offsets

    mlp_face_kernel<<<gb, 256, 0, stream>>>(hv, mf_w0, mf_b0, mf_w1T, mf_b1, A);
    gather_agg<<<gn, 256, 0, stream>>>(A, cur, adj, G);
    layer_kernel<true,  true ><<<gb, 256, 0, stream>>>(G, A, g1_relT, g1_rootT, g1_rel_b, A);
    layer_kernel<false, true ><<<gb, 256, 0, stream>>>(A, nullptr, s1_w0T, nullptr, s1_b0, A);
    layer_kernel<false, true ><<<gb, 256, 0, stream>>>(A, nullptr, s1_w1T, nullptr, s1_b1, A);
    layer_kernel<false, true ><<<gb, 256, 0, stream>>>(A, nullptr, s1_w2T, nullptr, s1_b2, A);
    gather_agg<<<gn, 256, 0, stream>>>(A, cur, adj, G);
    layer_kernel<true,  false><<<gb, 256, 0, stream>>>(G, A, g2_relT, g2_rootT, g2_rel_b, A);
    mlp_face_kernel<<<gb, 256, 0, stream>>>(hv, mf_w0, mf_b0, mf_w1T, mf_b1, G);
    layer_kernel<true,  true ><<<gb, 256, 0, stream>>>(G, A, s2w0loT, s2w0hiT, s2_b0, G);
    layer_kernel<false, true ><<<gb, 256, 0, stream>>>(G, nullptr, s2_w1T, nullptr, s2_b1, G);
    final_kernel<<<gb, 256, 0, stream>>>(G, s2_w2, s2_b2, (float*)d_out);
  } else {
    // ---- atomic-scatter fallback (256e6 ws) ----
    mlp_face_kernel<<<gb, 256, 0, stream>>>(hv, mf_w0, mf_b0, mf_w1T, mf_b1, A);
    (void)hipMemsetAsync(G, 0, ACT_BYTES, stream);
    scatter_kernel<<<4096, 256, 0, stream>>>(A, ei, (__half2*)G);
    layer_kernel<true,  true ><<<gb, 256, 0, stream>>>(G, A, g1_relT, g1_rootT, g1_rel_b, A);
    layer_kernel<false, true ><<<gb, 256, 0, stream>>>(A, nullptr, s1_w0T, nullptr, s1_b0, A);
    layer_kernel<false, true ><<<gb, 256, 0, stream>>>(A, nullptr, s1_w1T, nullptr, s1_b1, A);
    layer_kernel<false, true ><<<gb, 256, 0, stream>>>(A, nullptr, s1_w2T, nullptr, s1_b2, A);
    (void)hipMemsetAsync(G, 0, ACT_BYTES, stream);
    scatter_kernel<<<4096, 256, 0, stream>>>(A, ei, (__half2*)G);
    layer_kernel<true,  false><<<gb, 256, 0, stream>>>(G, A, g2_relT, g2_rootT, g2_rel_b, A);
    mlp_face_kernel<<<gb, 256, 0, stream>>>(hv, mf_w0, mf_b0, mf_w1T, mf_b1, G);
    layer_kernel<true,  true ><<<gb, 256, 0, stream>>>(G, A, s2w0loT, s2w0hiT, s2_b0, G);
    layer_kernel<false, true ><<<gb, 256, 0, stream>>>(G, nullptr, s2_w1T, nullptr, s2_b1, G);
    final_kernel<<<gb, 256, 0, stream>>>(G, s2_w2, s2_b2, (float*)d_out);
  }
}